// Round 1
// baseline (243.721 us; speedup 1.0000x reference)
//
#include <hip/hip_runtime.h>

#define BATCH       65536
#define FEAT        256
#define NUM_CLASSES 10000
#define ALPHA       0.5f

// ---------------------------------------------------------------------------
// Kernel 1: per-sample gather + diff + scatter-add + loss
// 4 waves per block, one sample per wave. Each lane handles 4 features
// (float4 = 16B/lane x 64 lanes = one full 1KB row, coalesced).
// ---------------------------------------------------------------------------
__global__ __launch_bounds__(256) void center_sample_kernel(
    const float* __restrict__ y_pred,
    const float* __restrict__ centers,
    const int*   __restrict__ y_true,
    float*       __restrict__ loss,
    float*       __restrict__ delta,
    float*       __restrict__ counts)
{
    const int wave = threadIdx.x >> 6;           // 0..3
    const int lane = threadIdx.x & 63;           // 0..63
    const int i    = blockIdx.x * 4 + wave;      // sample index
    if (i >= BATCH) return;

    const int c = y_true[i];

    const float4* yp = reinterpret_cast<const float4*>(y_pred  + (size_t)i * FEAT);
    const float4* ce = reinterpret_cast<const float4*>(centers + (size_t)c * FEAT);

    float4 a = yp[lane];
    float4 b = ce[lane];

    float4 d;
    d.x = b.x - a.x;
    d.y = b.y - a.y;
    d.z = b.z - a.z;
    d.w = b.w - a.w;

    // scatter-add into per-class delta accumulator
    float* dp = delta + (size_t)c * FEAT + (size_t)lane * 4;
    atomicAdd(dp + 0, d.x);
    atomicAdd(dp + 1, d.y);
    atomicAdd(dp + 2, d.z);
    atomicAdd(dp + 3, d.w);

    // loss = sum(diff^2) over the row; wave64 butterfly reduce
    float s = d.x * d.x + d.y * d.y + d.z * d.z + d.w * d.w;
    #pragma unroll
    for (int off = 32; off > 0; off >>= 1)
        s += __shfl_down(s, off, 64);

    if (lane == 0) {
        loss[i] = s;
        atomicAdd(counts + c, 1.0f);
    }
}

// ---------------------------------------------------------------------------
// Kernel 2: new_centers = centers - ALPHA * delta / (counts + 1)
// Each thread does one float4; a wave (64 lanes x 4) covers exactly one
// class row of 256 floats, so counts[class] is wave-uniform.
// ---------------------------------------------------------------------------
__global__ __launch_bounds__(256) void center_update_kernel(
    const float* __restrict__ centers,
    const float* __restrict__ delta,
    const float* __restrict__ counts,
    float*       __restrict__ new_centers)
{
    const size_t idx = (size_t)blockIdx.x * blockDim.x + threadIdx.x;
    const size_t e   = idx * 4;
    if (e >= (size_t)NUM_CLASSES * FEAT) return;

    float4 cv = *reinterpret_cast<const float4*>(centers + e);
    float4 dv = *reinterpret_cast<const float4*>(delta + e);
    float  cnt = counts[e / FEAT];
    float  scale = ALPHA / (cnt + 1.0f);

    float4 o;
    o.x = cv.x - dv.x * scale;
    o.y = cv.y - dv.y * scale;
    o.z = cv.z - dv.z * scale;
    o.w = cv.w - dv.w * scale;

    *reinterpret_cast<float4*>(new_centers + e) = o;
}

extern "C" void kernel_launch(void* const* d_in, const int* in_sizes, int n_in,
                              void* d_out, int out_size, void* d_ws, size_t ws_size,
                              hipStream_t stream)
{
    const float* y_pred  = (const float*)d_in[0];
    const float* centers = (const float*)d_in[1];
    const int*   y_true  = (const int*)d_in[2];

    float* out         = (float*)d_out;
    float* loss        = out;                 // [BATCH] (B x 1)
    float* new_centers = out + BATCH;         // [NUM_CLASSES x FEAT]

    float* delta  = (float*)d_ws;                                // [C*F]
    float* counts = delta + (size_t)NUM_CLASSES * FEAT;          // [C]

    // Zero accumulators every call (ws is poisoned once, never re-poisoned).
    hipMemsetAsync(d_ws, 0,
                   ((size_t)NUM_CLASSES * FEAT + NUM_CLASSES) * sizeof(float),
                   stream);

    center_sample_kernel<<<BATCH / 4, 256, 0, stream>>>(
        y_pred, centers, y_true, loss, delta, counts);

    const size_t n_vec4 = (size_t)NUM_CLASSES * FEAT / 4;        // 640000
    center_update_kernel<<<(n_vec4 + 255) / 256, 256, 0, stream>>>(
        centers, delta, counts, new_centers);
}

// Round 2
// 61.144 us; speedup vs baseline: 3.9860x; 3.9860x over previous
//
#include <hip/hip_runtime.h>

#define BATCH       65536
#define FEAT        256
#define NUM_CLASSES 10000
#define ALPHA       0.5f

// ---------------------------------------------------------------------------
// Phase 1: integer histogram of class labels
// ---------------------------------------------------------------------------
__global__ __launch_bounds__(256) void hist_kernel(const int* __restrict__ y_true,
                                                   int* __restrict__ hist)
{
    int i = blockIdx.x * 256 + threadIdx.x;
    if (i < BATCH) atomicAdd(&hist[y_true[i]], 1);
}

// ---------------------------------------------------------------------------
// Phase 2: single-block exclusive scan over NUM_CLASSES (10000) elements.
// Writes both offsets (stable copy) and cursor (consumed by scatter).
// ---------------------------------------------------------------------------
__global__ __launch_bounds__(1024) void scan_kernel(const int* __restrict__ hist,
                                                    int* __restrict__ offsets,
                                                    int* __restrict__ cursor)
{
    __shared__ int lds[1024];
    __shared__ int carry_s;
    if (threadIdx.x == 0) carry_s = 0;
    __syncthreads();

    for (int base = 0; base < NUM_CLASSES; base += 1024) {
        int i = base + (int)threadIdx.x;
        int v = (i < NUM_CLASSES) ? hist[i] : 0;
        lds[threadIdx.x] = v;
        __syncthreads();
        // Hillis-Steele inclusive scan
        for (int off = 1; off < 1024; off <<= 1) {
            int t = (threadIdx.x >= (unsigned)off) ? lds[threadIdx.x - off] : 0;
            __syncthreads();
            lds[threadIdx.x] += t;
            __syncthreads();
        }
        int incl = lds[threadIdx.x];
        int excl = incl - v;
        int cb = carry_s;
        if (i < NUM_CLASSES) {
            offsets[i] = cb + excl;
            cursor[i]  = cb + excl;
        }
        __syncthreads();                       // everyone done reading carry_s
        if (threadIdx.x == 1023) carry_s = cb + incl;   // incl of last = tile sum
        __syncthreads();
    }
}

// ---------------------------------------------------------------------------
// Phase 3: scatter sample indices into class-sorted order
// ---------------------------------------------------------------------------
__global__ __launch_bounds__(256) void scatter_kernel(const int* __restrict__ y_true,
                                                      int* __restrict__ cursor,
                                                      int* __restrict__ sidx)
{
    int i = blockIdx.x * 256 + threadIdx.x;
    if (i < BATCH) {
        int c = y_true[i];
        int pos = atomicAdd(&cursor[c], 1);
        sidx[pos] = i;
    }
}

// ---------------------------------------------------------------------------
// Phase 4: one wave per class. Gather the class's y_pred rows (1KB coalesced
// per row), accumulate sum_y in registers, emit per-sample loss, then write
// new_centers directly: delta = n*c - sum_y; new = c - ALPHA*delta/(n+1).
// No float atomics anywhere.
// ---------------------------------------------------------------------------
__global__ __launch_bounds__(256) void class_kernel(
    const float* __restrict__ y_pred,
    const float* __restrict__ centers,
    const int*   __restrict__ hist,
    const int*   __restrict__ offsets,
    const int*   __restrict__ sidx,
    float*       __restrict__ loss,
    float*       __restrict__ new_centers)
{
    const int wave = threadIdx.x >> 6;
    const int lane = threadIdx.x & 63;
    const int c    = blockIdx.x * 4 + wave;      // exact: 2500*4 = 10000
    if (c >= NUM_CLASSES) return;

    const int n    = hist[c];
    const int base = offsets[c];

    float4 cv = reinterpret_cast<const float4*>(centers + (size_t)c * FEAT)[lane];
    float4 s  = make_float4(0.f, 0.f, 0.f, 0.f);

    for (int k0 = 0; k0 < n; k0 += 64) {
        const int nb = min(64, n - k0);
        // coalesced preload of up to 64 sample indices, broadcast via shfl
        int myidx = (lane < nb) ? sidx[base + k0 + lane] : 0;
        for (int k = 0; k < nb; ++k) {
            const int idx = __shfl(myidx, k, 64);
            float4 y = reinterpret_cast<const float4*>(y_pred + (size_t)idx * FEAT)[lane];
            s.x += y.x; s.y += y.y; s.z += y.z; s.w += y.w;

            float dx = cv.x - y.x, dy = cv.y - y.y,
                  dz = cv.z - y.z, dw = cv.w - y.w;
            float l = dx*dx + dy*dy + dz*dz + dw*dw;
            #pragma unroll
            for (int off = 32; off > 0; off >>= 1)
                l += __shfl_down(l, off, 64);
            if (lane == 0) loss[idx] = l;
        }
    }

    const float fn    = (float)n;
    const float scale = ALPHA / (fn + 1.0f);
    float4 o;
    o.x = cv.x - (fn * cv.x - s.x) * scale;
    o.y = cv.y - (fn * cv.y - s.y) * scale;
    o.z = cv.z - (fn * cv.z - s.z) * scale;
    o.w = cv.w - (fn * cv.w - s.w) * scale;
    reinterpret_cast<float4*>(new_centers + (size_t)c * FEAT)[lane] = o;
}

extern "C" void kernel_launch(void* const* d_in, const int* in_sizes, int n_in,
                              void* d_out, int out_size, void* d_ws, size_t ws_size,
                              hipStream_t stream)
{
    const float* y_pred  = (const float*)d_in[0];
    const float* centers = (const float*)d_in[1];
    const int*   y_true  = (const int*)d_in[2];

    float* out         = (float*)d_out;
    float* loss        = out;                 // [BATCH]
    float* new_centers = out + BATCH;         // [NUM_CLASSES * FEAT]

    int* hist    = (int*)d_ws;                // [C]
    int* offsets = hist + NUM_CLASSES;        // [C]
    int* cursor  = offsets + NUM_CLASSES;     // [C]
    int* sidx    = cursor + NUM_CLASSES;      // [BATCH]

    // Only the histogram needs zeroing each call.
    hipMemsetAsync(hist, 0, NUM_CLASSES * sizeof(int), stream);

    hist_kernel   <<<BATCH / 256, 256, 0, stream>>>(y_true, hist);
    scan_kernel   <<<1, 1024, 0, stream>>>(hist, offsets, cursor);
    scatter_kernel<<<BATCH / 256, 256, 0, stream>>>(y_true, cursor, sidx);
    class_kernel  <<<NUM_CLASSES / 4, 256, 0, stream>>>(
        y_pred, centers, hist, offsets, sidx, loss, new_centers);
}

// Round 3
// 50.656 us; speedup vs baseline: 4.8113x; 1.2071x over previous
//
#include <hip/hip_runtime.h>

#define BATCH       65536
#define FEAT        256
#define NUM_CLASSES 10000
#define ALPHA       0.5f

// ---------------------------------------------------------------------------
// Phase 0: zero the histogram (replaces hipMemsetAsync / rocclr fillBuffer)
// ---------------------------------------------------------------------------
__global__ __launch_bounds__(256) void zero_kernel(int* __restrict__ hist)
{
    int i = blockIdx.x * 256 + threadIdx.x;
    if (i < NUM_CLASSES) hist[i] = 0;
}

// ---------------------------------------------------------------------------
// Phase 1: integer histogram of class labels
// ---------------------------------------------------------------------------
__global__ __launch_bounds__(256) void hist_kernel(const int* __restrict__ y_true,
                                                   int* __restrict__ hist)
{
    int i = blockIdx.x * 256 + threadIdx.x;
    if (i < BATCH) atomicAdd(&hist[y_true[i]], 1);
}

// ---------------------------------------------------------------------------
// Phase 2: single-block exclusive scan over NUM_CLASSES (10000).
// Thread t serially accumulates 10 classes; 1024 partials are scanned with
// wave shfl-scans + a 16-element LDS scan. ~2 passes total, no Hillis-Steele.
// ---------------------------------------------------------------------------
__global__ __launch_bounds__(1024) void scan_kernel(const int* __restrict__ hist,
                                                    int* __restrict__ offsets,
                                                    int* __restrict__ cursor)
{
    const int t    = threadIdx.x;
    const int lane = t & 63;
    const int wave = t >> 6;                 // 16 waves
    const int PER  = 10;                     // 1024*10 >= 10000
    const int base_i = t * PER;

    int v[PER];
    int sum = 0;
    #pragma unroll
    for (int j = 0; j < PER; ++j) {
        int i = base_i + j;
        int x = (i < NUM_CLASSES) ? hist[i] : 0;
        v[j] = sum;                          // exclusive local prefix
        sum += x;
    }

    // inclusive wave scan of per-thread sums
    int inc = sum;
    #pragma unroll
    for (int off = 1; off < 64; off <<= 1) {
        int u = __shfl_up(inc, off, 64);
        if (lane >= off) inc += u;
    }

    __shared__ int wsum[16];
    __shared__ int wbase[16];
    if (lane == 63) wsum[wave] = inc;
    __syncthreads();

    if (t < 16) {                            // scan the 16 wave totals
        int x = wsum[t];
        int winc = x;
        #pragma unroll
        for (int off = 1; off < 16; off <<= 1) {
            int u = __shfl_up(winc, off, 64);
            if (t >= off) winc += u;
        }
        wbase[t] = winc - x;                 // exclusive
    }
    __syncthreads();

    const int texcl = wbase[wave] + (inc - sum);   // exclusive prefix of thread t
    #pragma unroll
    for (int j = 0; j < PER; ++j) {
        int i = base_i + j;
        if (i < NUM_CLASSES) {
            int o = texcl + v[j];
            offsets[i] = o;
            cursor[i]  = o;
        }
    }
}

// ---------------------------------------------------------------------------
// Phase 3: scatter sample indices into class-sorted order
// ---------------------------------------------------------------------------
__global__ __launch_bounds__(256) void scatter_kernel(const int* __restrict__ y_true,
                                                      int* __restrict__ cursor,
                                                      int* __restrict__ sidx)
{
    int i = blockIdx.x * 256 + threadIdx.x;
    if (i < BATCH) {
        int c = y_true[i];
        int pos = atomicAdd(&cursor[c], 1);
        sidx[pos] = i;
    }
}

// ---------------------------------------------------------------------------
// Phase 4: one wave per class. Gather the class's y_pred rows (1KB coalesced
// per row), accumulate sum_y in registers, emit per-sample loss, then write
// new_centers directly: delta = n*c - sum_y; new = c - ALPHA*delta/(n+1).
// ---------------------------------------------------------------------------
__global__ __launch_bounds__(256) void class_kernel(
    const float* __restrict__ y_pred,
    const float* __restrict__ centers,
    const int*   __restrict__ hist,
    const int*   __restrict__ offsets,
    const int*   __restrict__ sidx,
    float*       __restrict__ loss,
    float*       __restrict__ new_centers)
{
    const int wave = threadIdx.x >> 6;
    const int lane = threadIdx.x & 63;
    const int c    = blockIdx.x * 4 + wave;      // exact: 2500*4 = 10000
    if (c >= NUM_CLASSES) return;

    const int n    = hist[c];
    const int base = offsets[c];

    float4 cv = reinterpret_cast<const float4*>(centers + (size_t)c * FEAT)[lane];
    float4 s  = make_float4(0.f, 0.f, 0.f, 0.f);

    for (int k0 = 0; k0 < n; k0 += 64) {
        const int nb = min(64, n - k0);
        int myidx = (lane < nb) ? sidx[base + k0 + lane] : 0;
        for (int k = 0; k < nb; ++k) {
            const int idx = __shfl(myidx, k, 64);
            float4 y = reinterpret_cast<const float4*>(y_pred + (size_t)idx * FEAT)[lane];
            s.x += y.x; s.y += y.y; s.z += y.z; s.w += y.w;

            float dx = cv.x - y.x, dy = cv.y - y.y,
                  dz = cv.z - y.z, dw = cv.w - y.w;
            float l = dx*dx + dy*dy + dz*dz + dw*dw;
            #pragma unroll
            for (int off = 32; off > 0; off >>= 1)
                l += __shfl_down(l, off, 64);
            if (lane == 0) loss[idx] = l;
        }
    }

    const float fn    = (float)n;
    const float scale = ALPHA / (fn + 1.0f);
    float4 o;
    o.x = cv.x - (fn * cv.x - s.x) * scale;
    o.y = cv.y - (fn * cv.y - s.y) * scale;
    o.z = cv.z - (fn * cv.z - s.z) * scale;
    o.w = cv.w - (fn * cv.w - s.w) * scale;
    reinterpret_cast<float4*>(new_centers + (size_t)c * FEAT)[lane] = o;
}

extern "C" void kernel_launch(void* const* d_in, const int* in_sizes, int n_in,
                              void* d_out, int out_size, void* d_ws, size_t ws_size,
                              hipStream_t stream)
{
    const float* y_pred  = (const float*)d_in[0];
    const float* centers = (const float*)d_in[1];
    const int*   y_true  = (const int*)d_in[2];

    float* out         = (float*)d_out;
    float* loss        = out;                 // [BATCH]
    float* new_centers = out + BATCH;         // [NUM_CLASSES * FEAT]

    int* hist    = (int*)d_ws;                // [C]
    int* offsets = hist + NUM_CLASSES;        // [C]
    int* cursor  = offsets + NUM_CLASSES;     // [C]
    int* sidx    = cursor + NUM_CLASSES;      // [BATCH]

    zero_kernel   <<<(NUM_CLASSES + 255) / 256, 256, 0, stream>>>(hist);
    hist_kernel   <<<BATCH / 256, 256, 0, stream>>>(y_true, hist);
    scan_kernel   <<<1, 1024, 0, stream>>>(hist, offsets, cursor);
    scatter_kernel<<<BATCH / 256, 256, 0, stream>>>(y_true, cursor, sidx);
    class_kernel  <<<NUM_CLASSES / 4, 256, 0, stream>>>(
        y_pred, centers, hist, offsets, sidx, loss, new_centers);
}